// Round 7
// baseline (255.817 us; speedup 1.0000x reference)
//
#include <hip/hip_runtime.h>
#include <stdint.h>

#define I_DIM 2048
#define O_DIM 8192
#define T_TOK 512
#define NSTR  64
#define BK    64
#define NSTEP (I_DIM / BK)

#define TILE_B 32768  // bytes per (stripe,step): [hi 16KB | lo 16KB], pre-swizzled

// gemm7 LDS layout: A 8KB (32 rows x 128B, hi+lo) + B 32KB = 40KB -> 4 blocks/CU
#define A_HI 0
#define A_LO 4096
#define B_OFF 8192
#define SMEM7 40960

// workspace layout (peak ~70.6MB, proven-safe range)
#define WT_OFF   ((size_t)0)             // 64MB weight tiles
#define XC_OFF   ((size_t)67108864)      // 4MB xc f32
#define THR_OFF  ((size_t)71303168)      // 512KB thrs f32[64][2048]
#define PM_OFF   ((size_t)71827456)      // 2MB pm_part f32[64][8192]
#define PMB_OFF  ((size_t)73924608)      // 32KB pmb f32[8192]
#define CNT_OFF  ((size_t)73957376)      // 2KB counts i32[512]

typedef __attribute__((ext_vector_type(8))) short bf16x8;
typedef __attribute__((ext_vector_type(4))) float f32x4;
typedef __attribute__((ext_vector_type(4))) int i32x4;

__device__ __forceinline__ void gload16(const void* g, void* l) {
  __builtin_amdgcn_global_load_lds(
      (const __attribute__((address_space(1))) void*)g,
      (__attribute__((address_space(3))) void*)l, 16, 0, 0);
}

// k0: fused prep: xc = x - mu; thrs = thresholds*std; zero counts.
__global__ void cwic_prep(const float* __restrict__ x, const float* __restrict__ mu,
                          const float* __restrict__ thresholds,
                          const float* __restrict__ stdv, float* __restrict__ xc,
                          float* __restrict__ thrs, int* __restrict__ counts) {
  int idx = blockIdx.x * 256 + threadIdx.x;  // 262144 float4s of xc
  float4 xv = ((const float4*)x)[idx];
  float4 mv = ((const float4*)mu)[idx & 511];
  float4 r;
  r.x = xv.x - mv.x; r.y = xv.y - mv.y; r.z = xv.z - mv.z; r.w = xv.w - mv.w;
  ((float4*)xc)[idx] = r;
  if (idx < (NSTR * I_DIM) / 4) {  // 32768 float4s of thrs
    float4 t = ((const float4*)thresholds)[idx];
    float4 s = ((const float4*)stdv)[idx & 511];
    float4 ts;
    ts.x = t.x * s.x; ts.y = t.y * s.y; ts.z = t.z * s.z; ts.w = t.w * s.w;
    ((float4*)thrs)[idx] = ts;
  }
  if (idx < T_TOK) counts[idx] = 0;
}

// k1: weight split f32 -> bf16 hi/lo tiles (pre-swizzled LDS image) + post_mu partials.
__global__ __launch_bounds__(256) void cwic_wprep(const float* __restrict__ w,
                                                  const float* __restrict__ mu,
                                                  char* __restrict__ wt,
                                                  float* __restrict__ pm_part) {
  const int bp = blockIdx.x;  // 2048 = 64 stripes x 32 steps
  const int n = bp >> 5, step = bp & 31;
  const int tid = threadIdx.x;
  const int o = tid & 127, kh = tid >> 7;
  const float* wp = w + (size_t)(step * BK + kh * 32) * O_DIM + n * 128 + o;
  char* tb = wt + (size_t)bp * TILE_B;
  const int rowb = o * 128;
  const int swz = (o & 7) << 4;
  float pm = 0.0f;
  #pragma unroll
  for (int g = 0; g < 4; ++g) {
    unsigned hv[4], lv[4];
    unsigned hprev = 0, lprev = 0;
    #pragma unroll
    for (int e = 0; e < 8; ++e) {
      const int irow = step * BK + kh * 32 + g * 8 + e;
      float v = wp[(size_t)(g * 8 + e) * O_DIM];
      pm += mu[irow] * v;
      unsigned u = __builtin_bit_cast(unsigned, v);
      unsigned r = u + 0x7fffu + ((u >> 16) & 1u);
      unsigned short h = (unsigned short)(r >> 16);
      float hif = __builtin_bit_cast(float, r & 0xffff0000u);
      unsigned short lo = (unsigned short)(__builtin_bit_cast(unsigned, v - hif) >> 16);
      if ((e & 1) == 0) { hprev = h; lprev = lo; }
      else {
        hv[e >> 1] = hprev | (((unsigned)h) << 16);
        lv[e >> 1] = lprev | (((unsigned)lo) << 16);
      }
    }
    *(i32x4*)(tb + rowb + ((kh * 64 + g * 16) ^ swz)) = *(i32x4*)hv;
    *(i32x4*)(tb + 16384 + rowb + ((kh * 64 + g * 16) ^ swz)) = *(i32x4*)lv;
  }
  pm_part[(size_t)(step * 2 + kh) * O_DIM + n * 128 + o] = pm;
}

// k2: pmb[o] = bias[o] + sum_s pm_part[s][o] (fixed order, deterministic)
__global__ void cwic_pmb(const float* __restrict__ pm_part,
                         const float* __restrict__ bias, float* __restrict__ pmb) {
  int o = blockIdx.x * 256 + threadIdx.x;
  float s = bias[o];
  #pragma unroll 8
  for (int j = 0; j < 64; ++j) s += pm_part[(size_t)j * O_DIM + o];
  pmb[o] = s;
}

// k3: masked GEMM, token-split. Block = 32 tokens x 128 outputs (one stripe), 4
// waves 2x2 (wave tile 16x64). A = (|xc|>thr ? xc : 0) staged cooperatively in
// LDS (hi/lo bf16, 8 elem/thread/step); B via global_load_lds from pre-split
// tiles (single-buffer, 2 barriers/step — gemm3-proven skeleton). 40KB LDS ->
// 4 blocks/CU, grid 1024 -> 16 waves/CU. Counts fused into A-build.
__global__ __launch_bounds__(256, 4) void cwic_gemm7(
    const float* __restrict__ xc, const char* __restrict__ wt,
    const float* __restrict__ thrs, const float* __restrict__ pmb,
    float* __restrict__ y, int* __restrict__ counts) {
  extern __shared__ char smem[];
  const int b = blockIdx.x;
  // XCD swizzle: all 16 token-tiles of one stripe land on one XCD -> B L2-hot.
  const int nid = (b & 7) * 128 + (b >> 3);
  const int n = nid >> 4, th = nid & 15;
  const int trow0 = th * 32, ocol0 = n * 128;
  const int tid = threadIdx.x;
  const int lane = tid & 63, wid = tid >> 6;
  const int wr = wid >> 1, wc = wid & 1;
  const int l15 = lane & 15, l4 = lane >> 4;

  const int t_loc = tid >> 3, kq = tid & 7;  // A staging: token row (0..31), k-octet
  const float* xrow = xc + (size_t)(trow0 + t_loc) * I_DIM + kq * 8;
  const float* thg = thrs + (size_t)n * I_DIM + kq * 8;
  const char* wtb = wt + (size_t)(n * NSTEP) * TILE_B;

  f32x4 acc[4];
  #pragma unroll
  for (int ni = 0; ni < 4; ++ni) acc[ni] = (f32x4)(0.0f);

  float4 xr[2][2], tr[2][2];
  int cnt = 0;

  // prefetch xc/thr for step 0
  xr[0][0] = *(const float4*)(xrow);
  xr[0][1] = *(const float4*)(xrow + 4);
  tr[0][0] = *(const float4*)(thg);
  tr[0][1] = *(const float4*)(thg + 4);

  for (int step = 0; step < NSTEP; ++step) {
    const int cb = step & 1, nb = cb ^ 1;
    // ---- stage B(step): 8 x global_load_lds(16B) from pre-swizzled tiles ----
    {
      const char* bs = wtb + (size_t)step * TILE_B + tid * 16;
      #pragma unroll
      for (int j = 0; j < 8; ++j)
        gload16(bs + j * 4096, smem + B_OFF + j * 4096 + tid * 16);
    }
    // ---- prefetch xc/thr for step+1 ----
    {
      const int kk1 = (step + 1 < NSTEP) ? (step + 1) * BK : step * BK;
      xr[nb][0] = *(const float4*)(xrow + kk1);
      xr[nb][1] = *(const float4*)(xrow + kk1 + 4);
      tr[nb][0] = *(const float4*)(thg + kk1);
      tr[nb][1] = *(const float4*)(thg + kk1 + 4);
    }
    // ---- A-build(step): mask+count + integer hi/lo split (verified bits) ----
    {
      const float4 x0 = xr[cb][0], x1 = xr[cb][1];
      const float4 t0 = tr[cb][0], t1 = tr[cb][1];
      const float xs[8] = {x0.x, x0.y, x0.z, x0.w, x1.x, x1.y, x1.z, x1.w};
      const float ts[8] = {t0.x, t0.y, t0.z, t0.w, t1.x, t1.y, t1.z, t1.w};
      unsigned hv[4], lv[4];
      unsigned hprev = 0, lprev = 0;
      #pragma unroll
      for (int e = 0; e < 8; ++e) {
        bool keep = fabsf(xs[e]) > ts[e];
        cnt += keep ? 1 : 0;
        float a = keep ? xs[e] : 0.0f;
        unsigned u = __builtin_bit_cast(unsigned, a);
        unsigned rr = u + 0x7fffu + ((u >> 16) & 1u);
        unsigned short h = (unsigned short)(rr >> 16);
        float hf = __builtin_bit_cast(float, rr & 0xffff0000u);
        unsigned short lo = (unsigned short)(__builtin_bit_cast(unsigned, a - hf) >> 16);
        if ((e & 1) == 0) { hprev = h; lprev = lo; }
        else {
          hv[e >> 1] = hprev | (((unsigned)h) << 16);
          lv[e >> 1] = lprev | (((unsigned)lo) << 16);
        }
      }
      const int ad = t_loc * 128 + ((kq * 16) ^ ((t_loc & 7) << 4));
      *(i32x4*)(smem + A_HI + ad) = *(i32x4*)hv;
      *(i32x4*)(smem + A_LO + ad) = *(i32x4*)lv;
    }
    __syncthreads();  // drains B gloads (vmcnt0) + A-writes visible
    // ---- compute: 2 K32 substeps, 20 ds_read_b128 + 24 MFMA per step ----
    __builtin_amdgcn_s_setprio(1);
    #pragma unroll
    for (int s32 = 0; s32 < 2; ++s32) {
      const int r = wr * 16 + l15;
      const int ada = r * 128 + (((s32 * 64) + l4 * 16) ^ ((r & 7) << 4));
      bf16x8 afh = *(const bf16x8*)(smem + A_HI + ada);
      bf16x8 afl = *(const bf16x8*)(smem + A_LO + ada);
      #pragma unroll
      for (int ni = 0; ni < 4; ++ni) {
        const int o = wc * 64 + ni * 16 + l15;
        const int adb = o * 128 + (((s32 * 64) + l4 * 16) ^ ((o & 7) << 4));
        bf16x8 bh = *(const bf16x8*)(smem + B_OFF + adb);
        bf16x8 bl = *(const bf16x8*)(smem + B_OFF + 16384 + adb);
        acc[ni] = __builtin_amdgcn_mfma_f32_16x16x32_bf16(afh, bh, acc[ni], 0, 0, 0);
        acc[ni] = __builtin_amdgcn_mfma_f32_16x16x32_bf16(afh, bl, acc[ni], 0, 0, 0);
        acc[ni] = __builtin_amdgcn_mfma_f32_16x16x32_bf16(afl, bh, acc[ni], 0, 0, 0);
      }
    }
    __builtin_amdgcn_s_setprio(0);
    __syncthreads();  // protect A/B LDS before next step's staging
  }

  // ---- mask-count reduce: 8 threads (kq) share one token row ----
  cnt += __shfl_xor(cnt, 1);
  cnt += __shfl_xor(cnt, 2);
  cnt += __shfl_xor(cnt, 4);
  if (kq == 0) atomicAdd(&counts[trow0 + t_loc], cnt);

  // ---- epilogue: y = acc + (post_mu + bias); C/D layout m89-verified ----
  #pragma unroll
  for (int ni = 0; ni < 4; ++ni) {
    const int o = ocol0 + wc * 64 + ni * 16 + l15;
    const float pv = pmb[o];
    const int row0 = trow0 + wr * 16 + l4 * 4;
    #pragma unroll
    for (int r = 0; r < 4; ++r) {
      y[(size_t)(row0 + r) * O_DIM + o] = acc[ni][r] + pv;
    }
  }
}

// k4: flops outputs. flops_sparse = 16777216 * cnt/(64*2048) = 128*cnt (exact).
__global__ void cwic_fin(const int* __restrict__ counts, float* __restrict__ outF) {
  int t = blockIdx.x * 256 + threadIdx.x;
  outF[t] = 16777216.0f;
  outF[T_TOK + t] = 128.0f * (float)counts[t];
}

extern "C" void kernel_launch(void* const* d_in, const int* in_sizes, int n_in,
                              void* d_out, int out_size, void* d_ws, size_t ws_size,
                              hipStream_t stream) {
  const float* x = (const float*)d_in[0];
  const float* w = (const float*)d_in[1];
  const float* bias = (const float*)d_in[2];
  const float* thresholds = (const float*)d_in[3];
  const float* mu = (const float*)d_in[4];
  const float* stdv = (const float*)d_in[5];
  float* y = (float*)d_out;

  char* ws = (char*)d_ws;
  char* wt = ws + WT_OFF;
  float* xc = (float*)(ws + XC_OFF);
  float* thrs = (float*)(ws + THR_OFF);
  float* pm_part = (float*)(ws + PM_OFF);
  float* pmb = (float*)(ws + PMB_OFF);
  int* counts = (int*)(ws + CNT_OFF);

  cwic_prep<<<1024, 256, 0, stream>>>(x, mu, thresholds, stdv, xc, thrs, counts);
  cwic_wprep<<<NSTR * NSTEP, 256, 0, stream>>>(w, mu, wt, pm_part);
  cwic_pmb<<<32, 256, 0, stream>>>(pm_part, bias, pmb);
  cwic_gemm7<<<1024, 256, SMEM7, stream>>>(xc, wt, thrs, pmb, y, counts);
  cwic_fin<<<2, 256, 0, stream>>>(counts, y + (size_t)T_TOK * O_DIM);
}

// Round 8
// 137.231 us; speedup vs baseline: 1.8641x; 1.8641x over previous
//
#include <hip/hip_runtime.h>
#include <stdint.h>

#define I_DIM 2048
#define O_DIM 8192
#define T_TOK 512
#define NSTR  64
#define BK    64
#define NSTEP (I_DIM / BK)

#define TILE_B 32768  // bytes per (stripe,step): [hi 16KB | lo 16KB], pre-swizzled

// gemm7 LDS layout: A 8KB (32 rows x 128B, hi+lo) + B 32KB = 40KB -> 4 blocks/CU
#define A_HI 0
#define A_LO 4096
#define B_OFF 8192
#define SMEM7 40960

// workspace layout (peak ~70.6MB)
#define WT_OFF   ((size_t)0)             // 64MB weight tiles
#define XC_OFF   ((size_t)67108864)      // 4MB xc f32
#define THR_OFF  ((size_t)71303168)      // 512KB thrs f32[64][2048]
#define PM_OFF   ((size_t)71827456)      // 2MB pm_part f32[64][8192]
#define PMB_OFF  ((size_t)73924608)      // 32KB pmb f32[8192]
#define CNT_OFF  ((size_t)73957376)      // 2KB counts i32[512]

typedef __attribute__((ext_vector_type(8))) short bf16x8;
typedef __attribute__((ext_vector_type(4))) float f32x4;
typedef __attribute__((ext_vector_type(4))) int i32x4;

__device__ __forceinline__ void gload16(const void* g, void* l) {
  __builtin_amdgcn_global_load_lds(
      (const __attribute__((address_space(1))) void*)g,
      (__attribute__((address_space(3))) void*)l, 16, 0, 0);
}

// k0: fused prep: xc = x - mu; thrs = thresholds*std; zero counts.
__global__ void cwic_prep(const float* __restrict__ x, const float* __restrict__ mu,
                          const float* __restrict__ thresholds,
                          const float* __restrict__ stdv, float* __restrict__ xc,
                          float* __restrict__ thrs, int* __restrict__ counts) {
  int idx = blockIdx.x * 256 + threadIdx.x;  // 262144 float4s of xc
  float4 xv = ((const float4*)x)[idx];
  float4 mv = ((const float4*)mu)[idx & 511];
  float4 r;
  r.x = xv.x - mv.x; r.y = xv.y - mv.y; r.z = xv.z - mv.z; r.w = xv.w - mv.w;
  ((float4*)xc)[idx] = r;
  if (idx < (NSTR * I_DIM) / 4) {  // 32768 float4s of thrs
    float4 t = ((const float4*)thresholds)[idx];
    float4 s = ((const float4*)stdv)[idx & 511];
    float4 ts;
    ts.x = t.x * s.x; ts.y = t.y * s.y; ts.z = t.z * s.z; ts.w = t.w * s.w;
    ((float4*)thrs)[idx] = ts;
  }
  if (idx < T_TOK) counts[idx] = 0;
}

// k1: weight split f32 -> bf16 hi/lo tiles (pre-swizzled LDS image) + post_mu partials.
__global__ __launch_bounds__(256) void cwic_wprep(const float* __restrict__ w,
                                                  const float* __restrict__ mu,
                                                  char* __restrict__ wt,
                                                  float* __restrict__ pm_part) {
  const int bp = blockIdx.x;  // 2048 = 64 stripes x 32 steps
  const int n = bp >> 5, step = bp & 31;
  const int tid = threadIdx.x;
  const int o = tid & 127, kh = tid >> 7;
  const float* wp = w + (size_t)(step * BK + kh * 32) * O_DIM + n * 128 + o;
  char* tb = wt + (size_t)bp * TILE_B;
  const int rowb = o * 128;
  const int swz = (o & 7) << 4;
  float pm = 0.0f;
  #pragma unroll
  for (int g = 0; g < 4; ++g) {
    unsigned hv[4], lv[4];
    unsigned hprev = 0, lprev = 0;
    #pragma unroll
    for (int e = 0; e < 8; ++e) {
      const int irow = step * BK + kh * 32 + g * 8 + e;
      float v = wp[(size_t)(g * 8 + e) * O_DIM];
      pm += mu[irow] * v;
      unsigned u = __builtin_bit_cast(unsigned, v);
      unsigned r = u + 0x7fffu + ((u >> 16) & 1u);
      unsigned short h = (unsigned short)(r >> 16);
      float hif = __builtin_bit_cast(float, r & 0xffff0000u);
      unsigned short lo = (unsigned short)(__builtin_bit_cast(unsigned, v - hif) >> 16);
      if ((e & 1) == 0) { hprev = h; lprev = lo; }
      else {
        hv[e >> 1] = hprev | (((unsigned)h) << 16);
        lv[e >> 1] = lprev | (((unsigned)lo) << 16);
      }
    }
    *(i32x4*)(tb + rowb + ((kh * 64 + g * 16) ^ swz)) = *(i32x4*)hv;
    *(i32x4*)(tb + 16384 + rowb + ((kh * 64 + g * 16) ^ swz)) = *(i32x4*)lv;
  }
  pm_part[(size_t)(step * 2 + kh) * O_DIM + n * 128 + o] = pm;
}

// k2: pmb[o] = bias[o] + sum_s pm_part[s][o] (fixed order, deterministic)
__global__ void cwic_pmb(const float* __restrict__ pm_part,
                         const float* __restrict__ bias, float* __restrict__ pmb) {
  int o = blockIdx.x * 256 + threadIdx.x;
  float s = bias[o];
  #pragma unroll 8
  for (int j = 0; j < 64; ++j) s += pm_part[(size_t)j * O_DIM + o];
  pmb[o] = s;
}

// k3: masked GEMM, token-split. Block = 32 tokens x 128 outputs (one stripe), 4
// waves 2x2 (wave tile 16x64). A = (|xc|>thr ? xc : 0) staged cooperatively in
// LDS; B via global_load_lds from pre-split tiles. 40KB LDS -> 4 blocks/CU.
// K-loop unrolled x2 with STATIC prefetch register names (rule #20: runtime-
// indexed ext_vector arrays spill to scratch — R7's 535MB WRITE_SIZE bug).
__global__ __launch_bounds__(256, 4) void cwic_gemm7(
    const float* __restrict__ xc, const char* __restrict__ wt,
    const float* __restrict__ thrs, const float* __restrict__ pmb,
    float* __restrict__ y, int* __restrict__ counts) {
  extern __shared__ char smem[];
  const int b = blockIdx.x;
  // XCD swizzle: all 16 token-tiles of one stripe land on one XCD -> B L2-hot.
  const int nid = (b & 7) * 128 + (b >> 3);
  const int n = nid >> 4, th = nid & 15;
  const int trow0 = th * 32, ocol0 = n * 128;
  const int tid = threadIdx.x;
  const int lane = tid & 63, wid = tid >> 6;
  const int wr = wid >> 1, wc = wid & 1;
  const int l15 = lane & 15, l4 = lane >> 4;

  const int t_loc = tid >> 3, kq = tid & 7;  // A staging: token row (0..31), k-octet
  const float* xrow = xc + (size_t)(trow0 + t_loc) * I_DIM + kq * 8;
  const float* thg = thrs + (size_t)n * I_DIM + kq * 8;
  const char* wtb = wt + (size_t)(n * NSTEP) * TILE_B;

  f32x4 acc[4];
  #pragma unroll
  for (int ni = 0; ni < 4; ++ni) acc[ni] = (f32x4)(0.0f);

  float4 xA0, xA1, tA0, tA1;  // current-step prefetch regs (static names)
  float4 xB0, xB1, tB0, tB1;  // next-step prefetch regs
  int cnt = 0;

  // prefetch xc/thr for step 0
  xA0 = *(const float4*)(xrow);
  xA1 = *(const float4*)(xrow + 4);
  tA0 = *(const float4*)(thg);
  tA1 = *(const float4*)(thg + 4);

#define STEP7(STEP_I, XC0, XC1, TC0, TC1, XN0, XN1, TN0, TN1)                  \
  {                                                                            \
    const int step_ = (STEP_I);                                                \
    /* stage B(step): 8 x global_load_lds(16B) from pre-swizzled tiles */      \
    {                                                                          \
      const char* bs_ = wtb + (size_t)step_ * TILE_B + tid * 16;               \
      _Pragma("unroll") for (int j_ = 0; j_ < 8; ++j_)                         \
        gload16(bs_ + j_ * 4096, smem + B_OFF + j_ * 4096 + tid * 16);         \
    }                                                                          \
    /* prefetch xc/thr for step+1 into the OTHER static regs */                \
    {                                                                          \
      const int kk1_ = (step_ + 1 < NSTEP) ? (step_ + 1) * BK : step_ * BK;    \
      XN0 = *(const float4*)(xrow + kk1_);                                     \
      XN1 = *(const float4*)(xrow + kk1_ + 4);                                 \
      TN0 = *(const float4*)(thg + kk1_);                                      \
      TN1 = *(const float4*)(thg + kk1_ + 4);                                  \
    }                                                                          \
    /* A-build(step): mask+count + integer hi/lo split (verified bits) */      \
    {                                                                          \
      const float xs_[8] = {XC0.x, XC0.y, XC0.z, XC0.w, XC1.x, XC1.y, XC1.z, XC1.w}; \
      const float ts_[8] = {TC0.x, TC0.y, TC0.z, TC0.w, TC1.x, TC1.y, TC1.z, TC1.w}; \
      unsigned hv_[4], lv_[4];                                                 \
      unsigned hprev_ = 0, lprev_ = 0;                                         \
      _Pragma("unroll") for (int e_ = 0; e_ < 8; ++e_) {                       \
        bool keep_ = fabsf(xs_[e_]) > ts_[e_];                                 \
        cnt += keep_ ? 1 : 0;                                                  \
        float a_ = keep_ ? xs_[e_] : 0.0f;                                     \
        unsigned u_ = __builtin_bit_cast(unsigned, a_);                        \
        unsigned rr_ = u_ + 0x7fffu + ((u_ >> 16) & 1u);                       \
        unsigned short h_ = (unsigned short)(rr_ >> 16);                       \
        float hf_ = __builtin_bit_cast(float, rr_ & 0xffff0000u);              \
        unsigned short lo_ = (unsigned short)(__builtin_bit_cast(unsigned, a_ - hf_) >> 16); \
        if ((e_ & 1) == 0) { hprev_ = h_; lprev_ = lo_; }                      \
        else {                                                                 \
          hv_[e_ >> 1] = hprev_ | (((unsigned)h_) << 16);                      \
          lv_[e_ >> 1] = lprev_ | (((unsigned)lo_) << 16);                     \
        }                                                                      \
      }                                                                        \
      const int ad_ = t_loc * 128 + ((kq * 16) ^ ((t_loc & 7) << 4));          \
      *(i32x4*)(smem + A_HI + ad_) = *(i32x4*)hv_;                             \
      *(i32x4*)(smem + A_LO + ad_) = *(i32x4*)lv_;                             \
    }                                                                          \
    __syncthreads(); /* drains B gloads + A-writes visible */                  \
    __builtin_amdgcn_s_setprio(1);                                             \
    _Pragma("unroll") for (int s32_ = 0; s32_ < 2; ++s32_) {                   \
      const int r_ = wr * 16 + l15;                                            \
      const int ada_ = r_ * 128 + (((s32_ * 64) + l4 * 16) ^ ((r_ & 7) << 4)); \
      bf16x8 afh_ = *(const bf16x8*)(smem + A_HI + ada_);                      \
      bf16x8 afl_ = *(const bf16x8*)(smem + A_LO + ada_);                      \
      _Pragma("unroll") for (int ni_ = 0; ni_ < 4; ++ni_) {                    \
        const int o_ = wc * 64 + ni_ * 16 + l15;                               \
        const int adb_ = o_ * 128 + (((s32_ * 64) + l4 * 16) ^ ((o_ & 7) << 4)); \
        bf16x8 bh_ = *(const bf16x8*)(smem + B_OFF + adb_);                    \
        bf16x8 bl_ = *(const bf16x8*)(smem + B_OFF + 16384 + adb_);            \
        acc[ni_] = __builtin_amdgcn_mfma_f32_16x16x32_bf16(afh_, bh_, acc[ni_], 0, 0, 0); \
        acc[ni_] = __builtin_amdgcn_mfma_f32_16x16x32_bf16(afh_, bl_, acc[ni_], 0, 0, 0); \
        acc[ni_] = __builtin_amdgcn_mfma_f32_16x16x32_bf16(afl_, bh_, acc[ni_], 0, 0, 0); \
      }                                                                        \
    }                                                                          \
    __builtin_amdgcn_s_setprio(0);                                             \
    __syncthreads(); /* protect A/B LDS before next step's staging */          \
  }

  for (int sp = 0; sp < NSTEP; sp += 2) {
    STEP7(sp,     xA0, xA1, tA0, tA1, xB0, xB1, tB0, tB1);
    STEP7(sp + 1, xB0, xB1, tB0, tB1, xA0, xA1, tA0, tA1);
  }
#undef STEP7

  // ---- mask-count reduce: 8 threads (kq) share one token row ----
  cnt += __shfl_xor(cnt, 1);
  cnt += __shfl_xor(cnt, 2);
  cnt += __shfl_xor(cnt, 4);
  if (kq == 0) atomicAdd(&counts[trow0 + t_loc], cnt);

  // ---- epilogue: y = acc + (post_mu + bias); C/D layout m89-verified ----
  #pragma unroll
  for (int ni = 0; ni < 4; ++ni) {
    const int o = ocol0 + wc * 64 + ni * 16 + l15;
    const float pv = pmb[o];
    const int row0 = trow0 + wr * 16 + l4 * 4;
    #pragma unroll
    for (int r = 0; r < 4; ++r) {
      y[(size_t)(row0 + r) * O_DIM + o] = acc[ni][r] + pv;
    }
  }
}

// k4: flops outputs. flops_sparse = 16777216 * cnt/(64*2048) = 128*cnt (exact).
__global__ void cwic_fin(const int* __restrict__ counts, float* __restrict__ outF) {
  int t = blockIdx.x * 256 + threadIdx.x;
  outF[t] = 16777216.0f;
  outF[T_TOK + t] = 128.0f * (float)counts[t];
}

extern "C" void kernel_launch(void* const* d_in, const int* in_sizes, int n_in,
                              void* d_out, int out_size, void* d_ws, size_t ws_size,
                              hipStream_t stream) {
  const float* x = (const float*)d_in[0];
  const float* w = (const float*)d_in[1];
  const float* bias = (const float*)d_in[2];
  const float* thresholds = (const float*)d_in[3];
  const float* mu = (const float*)d_in[4];
  const float* stdv = (const float*)d_in[5];
  float* y = (float*)d_out;

  char* ws = (char*)d_ws;
  char* wt = ws + WT_OFF;
  float* xc = (float*)(ws + XC_OFF);
  float* thrs = (float*)(ws + THR_OFF);
  float* pm_part = (float*)(ws + PM_OFF);
  float* pmb = (float*)(ws + PMB_OFF);
  int* counts = (int*)(ws + CNT_OFF);

  cwic_prep<<<1024, 256, 0, stream>>>(x, mu, thresholds, stdv, xc, thrs, counts);
  cwic_wprep<<<NSTR * NSTEP, 256, 0, stream>>>(w, mu, wt, pm_part);
  cwic_pmb<<<32, 256, 0, stream>>>(pm_part, bias, pmb);
  cwic_gemm7<<<1024, 256, SMEM7, stream>>>(xc, wt, thrs, pmb, y, counts);
  cwic_fin<<<2, 256, 0, stream>>>(counts, y + (size_t)T_TOK * O_DIM);
}